// Round 1
// baseline (591.263 us; speedup 1.0000x reference)
//
#include <hip/hip_runtime.h>
#include <hip/hip_bf16.h>

// Problem constants (fixed by reference)
#define OUT_F 4096
#define IN_F  4096
#define N_SUB 512
#define SUBD  8
#define M_DIM 8192   // 4*2048 rows of input
#define N_SPARSE 65536

typedef __bf16 bf16x8 __attribute__((ext_vector_type(8)));
typedef float floatx4 __attribute__((ext_vector_type(4)));

// ---------------------------------------------------------------------------
// Kernel 1: dequantize codebook -> bf16 weight [OUT_F][IN_F], with norms.
// One thread per (o, subvector) pair: 4096*512 = 2,097,152 threads.
// ---------------------------------------------------------------------------
__global__ __launch_bounds__(256) void build_weight(
    const float* __restrict__ cb,      // [N_CODES][8]
    const int*   __restrict__ map,     // [OUT_F][N_SUB]
    const int*   __restrict__ sa,      // [IN_F] subvector_assignment
    const float* __restrict__ rn,      // [IN_F] rowise (broadcast over columns)
    const float* __restrict__ cn,      // [OUT_F] colwise (broadcast over rows)
    __hip_bfloat16* __restrict__ W)    // [OUT_F][IN_F]
{
    int t  = blockIdx.x * blockDim.x + threadIdx.x;   // 0 .. 2M-1
    int o  = t >> 9;          // / N_SUB
    int j8 = t & (N_SUB - 1);
    int code = map[o * N_SUB + j8];
    float cno = cn[o];
    const float* cbp = cb + code * SUBD;
#pragma unroll
    for (int e = 0; e < SUBD; e++) {
        int j = j8 * SUBD + e;
        int i = sa[j];                        // identity in practice
        float v = cbp[e] * rn[i] * cno;
        W[(long)o * IN_F + i] = __float2bfloat16(v);
    }
}

// ---------------------------------------------------------------------------
// Kernel 2: sparse outlier override (after scaling, raw values).
// ---------------------------------------------------------------------------
__global__ __launch_bounds__(256) void sparse_scatter(
    const int*   __restrict__ idx,
    const float* __restrict__ sp,
    __hip_bfloat16* __restrict__ W, int n)
{
    int t = blockIdx.x * blockDim.x + threadIdx.x;
    if (t < n) W[idx[t]] = __float2bfloat16(sp[t]);
}

// ---------------------------------------------------------------------------
// Kernel 3: fp32 -> bf16 convert of the activation, 8 elems/thread.
// ---------------------------------------------------------------------------
__global__ __launch_bounds__(256) void cvt_bf16(
    const float* __restrict__ in, __hip_bfloat16* __restrict__ out, long n)
{
    long i = ((long)blockIdx.x * blockDim.x + threadIdx.x) * 8;
    if (i >= n) return;
    float4 f0 = *(const float4*)(in + i);
    float4 f1 = *(const float4*)(in + i + 4);
    union { __hip_bfloat16 h[8]; uint4 u; } pk;
    pk.h[0] = __float2bfloat16(f0.x); pk.h[1] = __float2bfloat16(f0.y);
    pk.h[2] = __float2bfloat16(f0.z); pk.h[3] = __float2bfloat16(f0.w);
    pk.h[4] = __float2bfloat16(f1.x); pk.h[5] = __float2bfloat16(f1.y);
    pk.h[6] = __float2bfloat16(f1.z); pk.h[7] = __float2bfloat16(f1.w);
    *(uint4*)(out + i) = pk.u;
}

// ---------------------------------------------------------------------------
// Kernel 4: bf16 GEMM, C[m][n] = sum_k A[m][k]*B[n][k] + bias[n]  (B^T layout).
// m97 structure: 128x128 tile, BK=32, 4 waves of 4x4 16x16x32 MFMA,
// global_load_lds width=16 staging, 2-barrier K-loop.
// ---------------------------------------------------------------------------
__device__ __forceinline__ void gl2lds16(const __hip_bfloat16* g, __hip_bfloat16* l)
{
    __builtin_amdgcn_global_load_lds(
        (const __attribute__((address_space(1))) unsigned int*)g,
        (__attribute__((address_space(3))) unsigned int*)l,
        16, 0, 0);
}

__global__ __launch_bounds__(256) void gemm_bt_bias(
    const __hip_bfloat16* __restrict__ A,   // [M][K]
    const __hip_bfloat16* __restrict__ B,   // [N][K]
    const float* __restrict__ bias,         // [N]
    float* __restrict__ C)                  // [M][N]
{
    constexpr int M = M_DIM, N = OUT_F, K = IN_F;
    constexpr int BK = 32;

    __shared__ __hip_bfloat16 sA[128 * BK];   // 8 KB
    __shared__ __hip_bfloat16 sB[128 * BK];   // 8 KB

    const int tid  = threadIdx.x;
    const int bm   = blockIdx.y;
    const int bn   = blockIdx.x;
    const int wave = tid >> 6;
    const int lane = tid & 63;
    const int wm   = (wave >> 1) * 64;   // wave row offset in tile
    const int wn   = (wave & 1) * 64;    // wave col offset in tile
    const int l16  = lane & 15;
    const int quad = lane >> 4;

    floatx4 acc[4][4] = {};

    // staging addressing: thread -> 16B chunk; lds dest must be lane-contiguous
    const int r0 = tid >> 2;            // 0..63 (row within half-tile)
    const int c0 = (tid & 3) * 8;       // k-offset in elements
    const __hip_bfloat16* gA0 = A + (long)(bm * 128 + r0) * K + c0;
    const __hip_bfloat16* gA1 = A + (long)(bm * 128 + 64 + r0) * K + c0;
    const __hip_bfloat16* gB0 = B + (long)(bn * 128 + r0) * K + c0;
    const __hip_bfloat16* gB1 = B + (long)(bn * 128 + 64 + r0) * K + c0;
    __hip_bfloat16* lA0 = sA + tid * 8;
    __hip_bfloat16* lA1 = sA + (tid + 256) * 8;
    __hip_bfloat16* lB0 = sB + tid * 8;
    __hip_bfloat16* lB1 = sB + (tid + 256) * 8;

    for (int kt = 0; kt < K; kt += BK) {
        gl2lds16(gA0 + kt, lA0);
        gl2lds16(gA1 + kt, lA1);
        gl2lds16(gB0 + kt, lB0);
        gl2lds16(gB1 + kt, lB1);
        __syncthreads();   // drains vmcnt -> LDS tile visible

        bf16x8 af[4], bfr[4];
#pragma unroll
        for (int mt = 0; mt < 4; mt++)
            af[mt] = *(const bf16x8*)(sA + (wm + mt * 16 + l16) * BK + quad * 8);
#pragma unroll
        for (int nt = 0; nt < 4; nt++)
            bfr[nt] = *(const bf16x8*)(sB + (wn + nt * 16 + l16) * BK + quad * 8);

#pragma unroll
        for (int mt = 0; mt < 4; mt++)
#pragma unroll
            for (int nt = 0; nt < 4; nt++)
                acc[mt][nt] = __builtin_amdgcn_mfma_f32_16x16x32_bf16(
                    af[mt], bfr[nt], acc[mt][nt], 0, 0, 0);

        __syncthreads();   // all reads done before next staging overwrite
    }

    // epilogue: C/D layout col=lane&15, row=quad*4+reg   [measured m89]
#pragma unroll
    for (int mt = 0; mt < 4; mt++) {
#pragma unroll
        for (int nt = 0; nt < 4; nt++) {
            int row = bm * 128 + wm + mt * 16 + quad * 4;
            int col = bn * 128 + wn + nt * 16 + l16;
            float bv = bias[col];
            float* cp = C + (long)row * N + col;
#pragma unroll
            for (int r = 0; r < 4; r++)
                cp[(long)r * N] = acc[mt][nt][r] + bv;
        }
    }
}

// ---------------------------------------------------------------------------
// launch
// ---------------------------------------------------------------------------
extern "C" void kernel_launch(void* const* d_in, const int* in_sizes, int n_in,
                              void* d_out, int out_size, void* d_ws, size_t ws_size,
                              hipStream_t stream)
{
    const float* input = (const float*)d_in[0];   // [4,2048,4096] fp32
    const float* cb    = (const float*)d_in[1];   // [4096,8]
    const int*   map   = (const int*)  d_in[2];   // [4096,512]
    const int*   sa    = (const int*)  d_in[3];   // [4096]
    const float* rn    = (const float*)d_in[4];   // [4096]
    const float* cn    = (const float*)d_in[5];   // [4096]
    const int*   sidx  = (const int*)  d_in[6];   // [65536]
    const float* sp    = (const float*)d_in[7];   // [65536]
    const float* bias  = (const float*)d_in[8];   // [4096]
    float* out = (float*)d_out;                   // [8192,4096] fp32

    // workspace layout: W bf16 (32 MB) | A bf16 (64 MB)
    __hip_bfloat16* W  = (__hip_bfloat16*)d_ws;
    __hip_bfloat16* Ab = (__hip_bfloat16*)((char*)d_ws + (size_t)OUT_F * IN_F * 2);

    // 1) dequant weight
    build_weight<<<(OUT_F * N_SUB) / 256, 256, 0, stream>>>(cb, map, sa, rn, cn, W);
    // 2) sparse override
    sparse_scatter<<<N_SPARSE / 256, 256, 0, stream>>>(sidx, sp, W, N_SPARSE);
    // 3) activation fp32 -> bf16
    const long n_act = (long)M_DIM * IN_F;
    cvt_bf16<<<(int)(n_act / 8 / 256), 256, 0, stream>>>(input, Ab, n_act);
    // 4) GEMM + bias
    dim3 grid(OUT_F / 128, M_DIM / 128);
    gemm_bt_bias<<<grid, 256, 0, stream>>>(Ab, W, bias, out);
}

// Round 2
// 560.620 us; speedup vs baseline: 1.0547x; 1.0547x over previous
//
#include <hip/hip_runtime.h>
#include <hip/hip_bf16.h>

// Problem constants (fixed by reference)
#define OUT_F 4096
#define IN_F  4096
#define N_SUB 512
#define SUBD  8
#define M_DIM 8192   // 4*2048 rows of input
#define N_SPARSE 65536

typedef __bf16 bf16x8 __attribute__((ext_vector_type(8)));
typedef float floatx4 __attribute__((ext_vector_type(4)));

// ---------------------------------------------------------------------------
// Kernel 1: dequantize codebook -> bf16 weight [OUT_F][IN_F], with norms.
// One thread per (o, subvector): 4096*512 threads. Vector path when the
// subvector_assignment is contiguous (it is: identity), scalar fallback else.
// ---------------------------------------------------------------------------
__global__ __launch_bounds__(256) void build_weight(
    const float* __restrict__ cb,      // [N_CODES][8]
    const int*   __restrict__ map,     // [OUT_F][N_SUB]
    const int*   __restrict__ sa,      // [IN_F] subvector_assignment
    const float* __restrict__ rn,      // [IN_F] rowise (broadcast over columns)
    const float* __restrict__ cn,      // [OUT_F] colwise (broadcast over rows)
    __hip_bfloat16* __restrict__ W)    // [OUT_F][IN_F]
{
    int t  = blockIdx.x * blockDim.x + threadIdx.x;   // 0 .. 2M-1
    int o  = t >> 9;          // / N_SUB
    int j8 = t & (N_SUB - 1);
    int j  = j8 * SUBD;
    int code = map[o * N_SUB + j8];
    float cno = cn[o];
    float4 c0 = *(const float4*)(cb + code * SUBD);
    float4 c1 = *(const float4*)(cb + code * SUBD + 4);
    int4 s0 = *(const int4*)(sa + j);
    int4 s1 = *(const int4*)(sa + j + 4);
    bool contig = (s0.x == j)     & (s0.y == j + 1) & (s0.z == j + 2) &
                  (s0.w == j + 3) & (s1.x == j + 4) & (s1.y == j + 5) &
                  (s1.z == j + 6) & (s1.w == j + 7);
    if (contig) {
        float4 r0 = *(const float4*)(rn + j);
        float4 r1 = *(const float4*)(rn + j + 4);
        union { __hip_bfloat16 h[8]; uint4 u; } pk;
        pk.h[0] = __float2bfloat16(c0.x * r0.x * cno);
        pk.h[1] = __float2bfloat16(c0.y * r0.y * cno);
        pk.h[2] = __float2bfloat16(c0.z * r0.z * cno);
        pk.h[3] = __float2bfloat16(c0.w * r0.w * cno);
        pk.h[4] = __float2bfloat16(c1.x * r1.x * cno);
        pk.h[5] = __float2bfloat16(c1.y * r1.y * cno);
        pk.h[6] = __float2bfloat16(c1.z * r1.z * cno);
        pk.h[7] = __float2bfloat16(c1.w * r1.w * cno);
        *(uint4*)(W + (long)o * IN_F + j) = pk.u;
    } else {
        float c[8] = {c0.x, c0.y, c0.z, c0.w, c1.x, c1.y, c1.z, c1.w};
        int   s[8] = {s0.x, s0.y, s0.z, s0.w, s1.x, s1.y, s1.z, s1.w};
#pragma unroll
        for (int e = 0; e < SUBD; e++)
            W[(long)o * IN_F + s[e]] = __float2bfloat16(c[e] * rn[s[e]] * cno);
    }
}

// ---------------------------------------------------------------------------
// Kernel 2: sparse outlier override (after scaling, raw values).
// ---------------------------------------------------------------------------
__global__ __launch_bounds__(256) void sparse_scatter(
    const int*   __restrict__ idx,
    const float* __restrict__ sp,
    __hip_bfloat16* __restrict__ W, int n)
{
    int t = blockIdx.x * blockDim.x + threadIdx.x;
    if (t < n) W[idx[t]] = __float2bfloat16(sp[t]);
}

// ---------------------------------------------------------------------------
// Kernel 3: fp32 -> bf16 convert of the activation, 8 elems/thread.
// ---------------------------------------------------------------------------
__global__ __launch_bounds__(256) void cvt_bf16(
    const float* __restrict__ in, __hip_bfloat16* __restrict__ out, long n)
{
    long i = ((long)blockIdx.x * blockDim.x + threadIdx.x) * 8;
    if (i >= n) return;
    float4 f0 = *(const float4*)(in + i);
    float4 f1 = *(const float4*)(in + i + 4);
    union { __hip_bfloat16 h[8]; uint4 u; } pk;
    pk.h[0] = __float2bfloat16(f0.x); pk.h[1] = __float2bfloat16(f0.y);
    pk.h[2] = __float2bfloat16(f0.z); pk.h[3] = __float2bfloat16(f0.w);
    pk.h[4] = __float2bfloat16(f1.x); pk.h[5] = __float2bfloat16(f1.y);
    pk.h[6] = __float2bfloat16(f1.z); pk.h[7] = __float2bfloat16(f1.w);
    *(uint4*)(out + i) = pk.u;
}

// ---------------------------------------------------------------------------
// Kernel 4: bf16 GEMM, C[m][n] = sum_k A[m][k]*B[n][k] + bias[n]  (B^T layout).
// m97 structure: 128x128 tile, BK=32, 4 waves of 4x4 16x16x32 MFMA,
// global_load_lds width=16 staging, 2-barrier K-loop.
// LDS bank-conflict fix: k-chunk of each staged row is XOR-swizzled by
// (row & 3) at the *global source* (LDS dest of global_load_lds is
// lane-forced); readers un-swizzle with quad ^ (l16 & 3).
// ---------------------------------------------------------------------------
__device__ __forceinline__ void gl2lds16(const __hip_bfloat16* g, __hip_bfloat16* l)
{
    __builtin_amdgcn_global_load_lds(
        (const __attribute__((address_space(1))) unsigned int*)g,
        (__attribute__((address_space(3))) unsigned int*)l,
        16, 0, 0);
}

__global__ __launch_bounds__(256) void gemm_bt_bias(
    const __hip_bfloat16* __restrict__ A,   // [M][K]
    const __hip_bfloat16* __restrict__ B,   // [N][K]
    const float* __restrict__ bias,         // [N]
    float* __restrict__ C)                  // [M][N]
{
    constexpr int N = OUT_F, K = IN_F;
    constexpr int BK = 32;

    __shared__ __hip_bfloat16 sA[128 * BK];   // 8 KB
    __shared__ __hip_bfloat16 sB[128 * BK];   // 8 KB

    const int tid  = threadIdx.x;
    const int bm   = blockIdx.y;
    const int bn   = blockIdx.x;
    const int wave = tid >> 6;
    const int lane = tid & 63;
    const int wm   = (wave >> 1) * 64;   // wave row offset in tile
    const int wn   = (wave & 1) * 64;    // wave col offset in tile
    const int l16  = lane & 15;
    const int quad = lane >> 4;
    const int sw   = l16 & 3;            // reader-side un-swizzle key

    floatx4 acc[4][4] = {};

    // staging addressing: thread -> 16B chunk; k-chunk source XOR-swizzled by row&3
    const int r0 = tid >> 2;                          // 0..63 row within half-tile
    const int c0 = (((tid & 3) ^ (r0 & 3)) ) * 8;     // swizzled k-offset (elements)
    const __hip_bfloat16* gA0 = A + (long)(bm * 128 + r0) * K + c0;
    const __hip_bfloat16* gA1 = A + (long)(bm * 128 + 64 + r0) * K + c0;
    const __hip_bfloat16* gB0 = B + (long)(bn * 128 + r0) * K + c0;
    const __hip_bfloat16* gB1 = B + (long)(bn * 128 + 64 + r0) * K + c0;
    __hip_bfloat16* lA0 = sA + tid * 8;
    __hip_bfloat16* lA1 = sA + (tid + 256) * 8;
    __hip_bfloat16* lB0 = sB + tid * 8;
    __hip_bfloat16* lB1 = sB + (tid + 256) * 8;

    for (int kt = 0; kt < K; kt += BK) {
        gl2lds16(gA0 + kt, lA0);
        gl2lds16(gA1 + kt, lA1);
        gl2lds16(gB0 + kt, lB0);
        gl2lds16(gB1 + kt, lB1);
        __syncthreads();   // drains vmcnt -> LDS tile visible

        bf16x8 af[4], bfr[4];
#pragma unroll
        for (int mt = 0; mt < 4; mt++) {
            int row = wm + mt * 16 + l16;
            af[mt] = *(const bf16x8*)(sA + (row * 4 + (quad ^ sw)) * 8);
        }
#pragma unroll
        for (int nt = 0; nt < 4; nt++) {
            int row = wn + nt * 16 + l16;
            bfr[nt] = *(const bf16x8*)(sB + (row * 4 + (quad ^ sw)) * 8);
        }

#pragma unroll
        for (int mt = 0; mt < 4; mt++)
#pragma unroll
            for (int nt = 0; nt < 4; nt++)
                acc[mt][nt] = __builtin_amdgcn_mfma_f32_16x16x32_bf16(
                    af[mt], bfr[nt], acc[mt][nt], 0, 0, 0);

        __syncthreads();   // all reads done before next staging overwrite
    }

    // epilogue: C/D layout col=lane&15, row=quad*4+reg   [measured m89]
#pragma unroll
    for (int mt = 0; mt < 4; mt++) {
#pragma unroll
        for (int nt = 0; nt < 4; nt++) {
            int row = bm * 128 + wm + mt * 16 + quad * 4;
            int col = bn * 128 + wn + nt * 16 + l16;
            float bv = bias[col];
            float* cp = C + (long)row * N + col;
#pragma unroll
            for (int r = 0; r < 4; r++)
                cp[(long)r * N] = acc[mt][nt][r] + bv;
        }
    }
}

// ---------------------------------------------------------------------------
// launch
// ---------------------------------------------------------------------------
extern "C" void kernel_launch(void* const* d_in, const int* in_sizes, int n_in,
                              void* d_out, int out_size, void* d_ws, size_t ws_size,
                              hipStream_t stream)
{
    const float* input = (const float*)d_in[0];   // [4,2048,4096] fp32
    const float* cb    = (const float*)d_in[1];   // [4096,8]
    const int*   map   = (const int*)  d_in[2];   // [4096,512]
    const int*   sa    = (const int*)  d_in[3];   // [4096]
    const float* rn    = (const float*)d_in[4];   // [4096]
    const float* cn    = (const float*)d_in[5];   // [4096]
    const int*   sidx  = (const int*)  d_in[6];   // [65536]
    const float* sp    = (const float*)d_in[7];   // [65536]
    const float* bias  = (const float*)d_in[8];   // [4096]
    float* out = (float*)d_out;                   // [8192,4096] fp32

    // workspace layout: W bf16 (32 MB) | A bf16 (64 MB)
    __hip_bfloat16* W  = (__hip_bfloat16*)d_ws;
    __hip_bfloat16* Ab = (__hip_bfloat16*)((char*)d_ws + (size_t)OUT_F * IN_F * 2);

    // 1) dequant weight
    build_weight<<<(OUT_F * N_SUB) / 256, 256, 0, stream>>>(cb, map, sa, rn, cn, W);
    // 2) sparse override
    sparse_scatter<<<N_SPARSE / 256, 256, 0, stream>>>(sidx, sp, W, N_SPARSE);
    // 3) activation fp32 -> bf16
    const long n_act = (long)M_DIM * IN_F;
    cvt_bf16<<<(int)(n_act / 8 / 256), 256, 0, stream>>>(input, Ab, n_act);
    // 4) GEMM + bias
    dim3 grid(OUT_F / 128, M_DIM / 128);
    gemm_bt_bias<<<grid, 256, 0, stream>>>(Ab, W, bias, out);
}

// Round 3
// 497.330 us; speedup vs baseline: 1.1889x; 1.1273x over previous
//
#include <hip/hip_runtime.h>
#include <hip/hip_bf16.h>

// Problem constants (fixed by reference)
#define OUT_F 4096
#define IN_F  4096
#define N_SUB 512
#define SUBD  8
#define M_DIM 8192   // 4*2048 rows of input
#define N_SPARSE 65536

typedef __bf16 bf16x8 __attribute__((ext_vector_type(8)));
typedef float floatx4 __attribute__((ext_vector_type(4)));

// ---------------------------------------------------------------------------
// Kernel 1: dequantize codebook -> bf16 weight [OUT_F][IN_F], with norms.
// Vector path when subvector_assignment is contiguous (identity), scalar else.
// ---------------------------------------------------------------------------
__global__ __launch_bounds__(256) void build_weight(
    const float* __restrict__ cb,      // [N_CODES][8]
    const int*   __restrict__ map,     // [OUT_F][N_SUB]
    const int*   __restrict__ sa,      // [IN_F]
    const float* __restrict__ rn,      // [IN_F] rowise (broadcast over columns)
    const float* __restrict__ cn,      // [OUT_F] colwise (broadcast over rows)
    __hip_bfloat16* __restrict__ W)    // [OUT_F][IN_F]
{
    int t  = blockIdx.x * blockDim.x + threadIdx.x;
    int o  = t >> 9;
    int j8 = t & (N_SUB - 1);
    int j  = j8 * SUBD;
    int code = map[o * N_SUB + j8];
    float cno = cn[o];
    float4 c0 = *(const float4*)(cb + code * SUBD);
    float4 c1 = *(const float4*)(cb + code * SUBD + 4);
    int4 s0 = *(const int4*)(sa + j);
    int4 s1 = *(const int4*)(sa + j + 4);
    bool contig = (s0.x == j)     & (s0.y == j + 1) & (s0.z == j + 2) &
                  (s0.w == j + 3) & (s1.x == j + 4) & (s1.y == j + 5) &
                  (s1.z == j + 6) & (s1.w == j + 7);
    if (contig) {
        float4 r0 = *(const float4*)(rn + j);
        float4 r1 = *(const float4*)(rn + j + 4);
        union { __hip_bfloat16 h[8]; uint4 u; } pk;
        pk.h[0] = __float2bfloat16(c0.x * r0.x * cno);
        pk.h[1] = __float2bfloat16(c0.y * r0.y * cno);
        pk.h[2] = __float2bfloat16(c0.z * r0.z * cno);
        pk.h[3] = __float2bfloat16(c0.w * r0.w * cno);
        pk.h[4] = __float2bfloat16(c1.x * r1.x * cno);
        pk.h[5] = __float2bfloat16(c1.y * r1.y * cno);
        pk.h[6] = __float2bfloat16(c1.z * r1.z * cno);
        pk.h[7] = __float2bfloat16(c1.w * r1.w * cno);
        *(uint4*)(W + (long)o * IN_F + j) = pk.u;
    } else {
        float c[8] = {c0.x, c0.y, c0.z, c0.w, c1.x, c1.y, c1.z, c1.w};
        int   s[8] = {s0.x, s0.y, s0.z, s0.w, s1.x, s1.y, s1.z, s1.w};
#pragma unroll
        for (int e = 0; e < SUBD; e++)
            W[(long)o * IN_F + s[e]] = __float2bfloat16(c[e] * rn[s[e]] * cno);
    }
}

// ---------------------------------------------------------------------------
// Kernel 2: sparse outlier override (after scaling, raw values).
// ---------------------------------------------------------------------------
__global__ __launch_bounds__(256) void sparse_scatter(
    const int*   __restrict__ idx,
    const float* __restrict__ sp,
    __hip_bfloat16* __restrict__ W, int n)
{
    int t = blockIdx.x * blockDim.x + threadIdx.x;
    if (t < n) W[idx[t]] = __float2bfloat16(sp[t]);
}

// ---------------------------------------------------------------------------
// Kernel 3: fp32 -> bf16 convert of the activation, 8 elems/thread.
// ---------------------------------------------------------------------------
__global__ __launch_bounds__(256) void cvt_bf16(
    const float* __restrict__ in, __hip_bfloat16* __restrict__ out, long n)
{
    long i = ((long)blockIdx.x * blockDim.x + threadIdx.x) * 8;
    if (i >= n) return;
    float4 f0 = *(const float4*)(in + i);
    float4 f1 = *(const float4*)(in + i + 4);
    union { __hip_bfloat16 h[8]; uint4 u; } pk;
    pk.h[0] = __float2bfloat16(f0.x); pk.h[1] = __float2bfloat16(f0.y);
    pk.h[2] = __float2bfloat16(f0.z); pk.h[3] = __float2bfloat16(f0.w);
    pk.h[4] = __float2bfloat16(f1.x); pk.h[5] = __float2bfloat16(f1.y);
    pk.h[6] = __float2bfloat16(f1.z); pk.h[7] = __float2bfloat16(f1.w);
    *(uint4*)(out + i) = pk.u;
}

// ---------------------------------------------------------------------------
// Kernel 4: bf16 GEMM, C[m][n] = sum_k A[m][k]*B[n][k] + bias[n]  (B^T layout).
// 128x128 tile, BK=64 (half the barriers of BK=32), 4 waves x (4x4 of
// 16x16x32 MFMA), global_load_lds width=16 staging.
// __launch_bounds__(256,4): cap total regs at 128 (64 acc AGPR + <=64 VGPR)
// -> 4 blocks/CU residency (was ~2.3 at 144 regs).
// Row stride is 128 B (bank-aligned), so 16B chunk position within each row
// is XOR-swizzled by row&7; the staging-side swizzle key (tid&7)^((tid>>3)&7)
// is invariant across the 4 sub-loads (32*i rows == 0 mod 8).
// ---------------------------------------------------------------------------
__device__ __forceinline__ void gl2lds16(const __hip_bfloat16* g, __hip_bfloat16* l)
{
    __builtin_amdgcn_global_load_lds(
        (const __attribute__((address_space(1))) unsigned int*)g,
        (__attribute__((address_space(3))) unsigned int*)l,
        16, 0, 0);
}

__global__ __launch_bounds__(256, 4) void gemm_bt_bias(
    const __hip_bfloat16* __restrict__ A,   // [M][K]
    const __hip_bfloat16* __restrict__ B,   // [N][K]
    const float* __restrict__ bias,         // [N]
    float* __restrict__ C)                  // [M][N]
{
    constexpr int N = OUT_F, K = IN_F;
    constexpr int BK = 64;

    __shared__ __hip_bfloat16 sA[128 * BK];   // 16 KB
    __shared__ __hip_bfloat16 sB[128 * BK];   // 16 KB

    const int tid  = threadIdx.x;
    const int bm   = blockIdx.y;
    const int bn   = blockIdx.x;
    const int wave = tid >> 6;
    const int lane = tid & 63;
    const int wm   = (wave >> 1) * 64;   // wave row offset in tile
    const int wn   = (wave & 1) * 64;    // wave col offset in tile
    const int l16  = lane & 15;
    const int quad = lane >> 4;

    floatx4 acc[4][4] = {};

    // staging: LDS chunk id = tid + 256*i  (i=0..3 per matrix)
    //   row = (tid>>3) + 32*i, chunk position p = tid&7,
    //   source k-chunk cc = p ^ (row&7) = (tid&7) ^ ((tid>>3)&7)  (i-invariant)
    const int sr = tid >> 3;                                   // 0..31
    const int sc = (((tid & 7) ^ ((tid >> 3) & 7))) * 8;       // swizzled k-elem
    const __hip_bfloat16* gA = A + (long)(bm * 128 + sr) * K + sc;
    const __hip_bfloat16* gB = B + (long)(bn * 128 + sr) * K + sc;
    __hip_bfloat16* lA = sA + tid * 8;
    __hip_bfloat16* lB = sB + tid * 8;

    for (int kt = 0; kt < K; kt += BK) {
#pragma unroll
        for (int i = 0; i < 4; i++)
            gl2lds16(gA + kt + (long)i * 32 * K, lA + i * 2048);
#pragma unroll
        for (int i = 0; i < 4; i++)
            gl2lds16(gB + kt + (long)i * 32 * K, lB + i * 2048);
        __syncthreads();   // drains vmcnt -> LDS tile visible

#pragma unroll
        for (int ks = 0; ks < 2; ks++) {
            bf16x8 af[4], bfr[4];
#pragma unroll
            for (int mt = 0; mt < 4; mt++) {
                int r = wm + mt * 16 + l16;
                af[mt] = *(const bf16x8*)(sA + r * BK + (((ks * 4 + quad) ^ (l16 & 7)) * 8));
            }
#pragma unroll
            for (int nt = 0; nt < 4; nt++) {
                int r = wn + nt * 16 + l16;
                bfr[nt] = *(const bf16x8*)(sB + r * BK + (((ks * 4 + quad) ^ (l16 & 7)) * 8));
            }
#pragma unroll
            for (int mt = 0; mt < 4; mt++)
#pragma unroll
                for (int nt = 0; nt < 4; nt++)
                    acc[mt][nt] = __builtin_amdgcn_mfma_f32_16x16x32_bf16(
                        af[mt], bfr[nt], acc[mt][nt], 0, 0, 0);
        }

        __syncthreads();   // all reads done before next staging overwrite
    }

    // epilogue: C/D layout col=lane&15, row=quad*4+reg   [measured m89]
#pragma unroll
    for (int mt = 0; mt < 4; mt++) {
#pragma unroll
        for (int nt = 0; nt < 4; nt++) {
            int row = bm * 128 + wm + mt * 16 + quad * 4;
            int col = bn * 128 + wn + nt * 16 + l16;
            float bv = bias[col];
            float* cp = C + (long)row * N + col;
#pragma unroll
            for (int r = 0; r < 4; r++)
                cp[(long)r * N] = acc[mt][nt][r] + bv;
        }
    }
}

// ---------------------------------------------------------------------------
// launch
// ---------------------------------------------------------------------------
extern "C" void kernel_launch(void* const* d_in, const int* in_sizes, int n_in,
                              void* d_out, int out_size, void* d_ws, size_t ws_size,
                              hipStream_t stream)
{
    const float* input = (const float*)d_in[0];   // [4,2048,4096] fp32
    const float* cb    = (const float*)d_in[1];   // [4096,8]
    const int*   map   = (const int*)  d_in[2];   // [4096,512]
    const int*   sa    = (const int*)  d_in[3];   // [4096]
    const float* rn    = (const float*)d_in[4];   // [4096]
    const float* cn    = (const float*)d_in[5];   // [4096]
    const int*   sidx  = (const int*)  d_in[6];   // [65536]
    const float* sp    = (const float*)d_in[7];   // [65536]
    const float* bias  = (const float*)d_in[8];   // [4096]
    float* out = (float*)d_out;                   // [8192,4096] fp32

    // workspace layout: W bf16 (32 MB) | A bf16 (64 MB)
    __hip_bfloat16* W  = (__hip_bfloat16*)d_ws;
    __hip_bfloat16* Ab = (__hip_bfloat16*)((char*)d_ws + (size_t)OUT_F * IN_F * 2);

    // 1) dequant weight
    build_weight<<<(OUT_F * N_SUB) / 256, 256, 0, stream>>>(cb, map, sa, rn, cn, W);
    // 2) sparse override
    sparse_scatter<<<N_SPARSE / 256, 256, 0, stream>>>(sidx, sp, W, N_SPARSE);
    // 3) activation fp32 -> bf16
    const long n_act = (long)M_DIM * IN_F;
    cvt_bf16<<<(int)(n_act / 8 / 256), 256, 0, stream>>>(input, Ab, n_act);
    // 4) GEMM + bias
    dim3 grid(OUT_F / 128, M_DIM / 128);
    gemm_bt_bias<<<grid, 256, 0, stream>>>(Ab, W, bias, out);
}